// Round 2
// baseline (276.300 us; speedup 1.0000x reference)
//
#include <hip/hip_runtime.h>

// Batched dynamic-filter cross-correlation:
// x: [128, 384, 384, 1] f32, k: [128, 8, 8, 1] f32
// out[b,i,j] = sum_{p,q} x[b,i+p,j+q] * k[b,p,q], out: [128, 377, 377, 1]

#define BATCH 128
#define Hh 384
#define Ww 384
#define KH 8
#define KW 8
#define OH 377
#define OW 377

#define TI 64                  // output rows per block
#define TJ 128                 // output cols per block
#define XRW (TI + KH - 1)      // 71 staged rows
#define XC4 34                 // float4 per staged row (136 floats >= 128+7)
#define XSTRIDE 136            // LDS row stride in floats (multiple of 4 -> b128 aligned)

// Per thread: 8 output rows x 4 output cols. Per wave (64 lanes):
//   c  = lane & 15  -> 4-col group (16 groups x 4 = 64 cols)
//   r4 = lane >> 4  -> 8-row group (4 groups x 8 = 32 rows)
// Wave grid 2x2 inside the block -> 64 rows x 128 cols.

__global__ __launch_bounds__(256, 4) void corr_kernel(
    const float* __restrict__ x,
    const float* __restrict__ k,
    float* __restrict__ out) {

    __shared__ float xs[XRW * XSTRIDE];   // 71*136*4 = 38,624 B

    const int tj = blockIdx.x;           // 0..2
    const int ti = blockIdx.y;           // 0..5
    const int b  = blockIdx.z;           // 0..127

    const int bi  = ti * TI;
    const int bj  = tj * TJ;
    const int tid = (int)threadIdx.x;

    // ---- stage x tile: rows bi..bi+70, cols bj..bj+135 (zero-fill OOB) ----
    const float* xb = x + (size_t)b * (Hh * Ww);
    for (int idx = tid; idx < XRW * XC4; idx += 256) {
        const int r    = idx / XC4;
        const int c4   = idx - r * XC4;
        const int grow = bi + r;
        const int gcol = bj + c4 * 4;
        float4 v = make_float4(0.f, 0.f, 0.f, 0.f);
        if (grow < Hh) {
            const float* rp = xb + (size_t)grow * Ww + gcol;
            if (gcol + 3 < Ww) {
                v = *(const float4*)rp;
            } else {
                if (gcol + 0 < Ww) v.x = rp[0];
                if (gcol + 1 < Ww) v.y = rp[1];
                if (gcol + 2 < Ww) v.z = rp[2];
                if (gcol + 3 < Ww) v.w = rp[3];
            }
        }
        *(float4*)(&xs[r * XSTRIDE + c4 * 4]) = v;
    }

    // ---- k through a uniform pointer with static indices -> SGPRs ----
    const float* kg = k + (size_t)b * (KH * KW);
    float ka[64];
#pragma unroll
    for (int i = 0; i < 64; ++i) ka[i] = kg[i];

    __syncthreads();

    // ---- compute ----
    const int w  = tid >> 6;             // wave 0..3
    const int l  = tid & 63;
    const int c  = l & 15;
    const int r4 = l >> 4;
    const int tr = (w >> 1) * 32 + r4 * 8;   // thread's first output row (local)
    const int tc = (w & 1) * 64 + c * 4;     // thread's first output col (local)

    float acc[8][4];
#pragma unroll
    for (int r = 0; r < 8; ++r)
#pragma unroll
        for (int cc = 0; cc < 4; ++cc) acc[r][cc] = 0.f;

#pragma unroll
    for (int s = 0; s < 15; ++s) {       // x rows tr+0 .. tr+14
        const float* rp = &xs[(tr + s) * XSTRIDE + tc];
        float4 a0 = *(const float4*)(rp + 0);
        float4 a1 = *(const float4*)(rp + 4);
        float4 a2 = *(const float4*)(rp + 8);
        float wv[12] = {a0.x, a0.y, a0.z, a0.w,
                        a1.x, a1.y, a1.z, a1.w,
                        a2.x, a2.y, a2.z, a2.w};
#pragma unroll
        for (int p = 0; p < 8; ++p) {
            // r = s - p must be in [0,8): compile-time predicate (s,p static)
            if (s - p < 0 || s - p > 7) continue;
            const int r = s - p;
#pragma unroll
            for (int cc = 0; cc < 4; ++cc)
#pragma unroll
                for (int q = 0; q < 8; ++q)
                    acc[r][cc] = fmaf(wv[cc + q], ka[p * 8 + q], acc[r][cc]);
        }
    }

    // ---- store (lane groups cover contiguous 64-col spans -> coalesced lines) ----
#pragma unroll
    for (int r = 0; r < 8; ++r) {
        const int orow = bi + tr + r;
        if (orow < OH) {
            float* ob = out + ((size_t)b * OH + orow) * OW;
#pragma unroll
            for (int cc = 0; cc < 4; ++cc) {
                const int ocol = bj + tc + cc;
                if (ocol < OW) ob[ocol] = acc[r][cc];
            }
        }
    }
}

extern "C" void kernel_launch(void* const* d_in, const int* in_sizes, int n_in,
                              void* d_out, int out_size, void* d_ws, size_t ws_size,
                              hipStream_t stream) {
    const float* x = (const float*)d_in[0];
    const float* k = (const float*)d_in[1];
    float* out = (float*)d_out;

    dim3 grid((OW + TJ - 1) / TJ,   // 3
              (OH + TI - 1) / TI,   // 6
              BATCH);               // 128
    dim3 block(256);
    hipLaunchKernelGGL(corr_kernel, grid, block, 0, stream, x, k, out);
}